// Round 22
// baseline (146.366 us; speedup 1.0000x reference)
//
#include <hip/hip_runtime.h>
#include <hip/hip_bf16.h>
#include <math.h>

typedef __hip_bfloat16 bf16;
using f32x4  = __attribute__((ext_vector_type(4))) float;
using f32x2  = __attribute__((ext_vector_type(2))) float;
using bf16x8 = __attribute__((ext_vector_type(8))) short;
using f16x2  = __attribute__((ext_vector_type(2))) _Float16;

constexpr int BS = 2, NQ = 22223, MROWS = 44446;
constexpr int LH[4] = {100, 50, 25, 13};
constexpr int LW[4] = {167, 84, 42, 21};
constexpr int LSTART[4] = {0, 16700, 20900, 21950};
// Padded levels: +1 left/top, +2 right/bottom (Wp=W+3, Hp=H+3)
constexpr int PLW[4] = {170, 87, 45, 24};
constexpr int PLSTART[4] = {0, 17510, 22121, 23381};
constexpr int PTOT = 23765;

constexpr int BM = 64;                // rows per block
constexpr int LDT = 40;               // LDS row stride (bf16): 80B
constexpr int GX = (MROWS + BM - 1) / BM;   // 695

// ---------------------------------------------------------------------------
__global__ __launch_bounds__(256) void prep_weights(
    const float* __restrict__ W_vp, const float* __restrict__ W_so,
    const float* __restrict__ W_aw, const float* __restrict__ W_op,
    const float* __restrict__ b_so, const float* __restrict__ b_aw,
    bf16* __restrict__ Wt_vp, bf16* __restrict__ Wt_cat,
    bf16* __restrict__ Wt_op, float* __restrict__ bcat)
{
    int i = blockIdx.x * 256 + threadIdx.x;
    if (i < 256 * 256) {
        int n = i >> 8, k = i & 255;
        Wt_vp[i] = __float2bfloat16(W_vp[k * 256 + n]);
        Wt_op[i] = __float2bfloat16(W_op[k * 256 + n]);
    }
    if (i < 384 * 256) {
        int n = i >> 8, k = i & 255;
        float v = (n < 256) ? W_so[k * 256 + n] : W_aw[k * 128 + (n - 256)];
        Wt_cat[i] = __float2bfloat16(v);
    }
    if (i < 384) bcat[i] = (i < 256) ? b_so[i] : b_aw[i - 256];
}

// Map batch-local value pixel -> level-local padded pixel index (+1,+1 offset)
__device__ inline int pad_base_idx(int pix) {
    if (pix < LSTART[1])      { int y = pix / 167;                  int x = pix - y * 167;                return PLSTART[0] + (y + 1) * 170 + (x + 1); }
    else if (pix < LSTART[2]) { int rel = pix - LSTART[1]; int y = rel / 84; int x = rel - y * 84;        return PLSTART[1] + (y + 1) * 87  + (x + 1); }
    else if (pix < LSTART[3]) { int rel = pix - LSTART[2]; int y = rel / 42; int x = rel - y * 42;        return PLSTART[2] + (y + 1) * 45  + (x + 1); }
    else                      { int rel = pix - LSTART[3]; int y = rel / 21; int x = rel - y * 21;        return PLSTART[3] + (y + 1) * 24  + (x + 1); }
}

// ---------------------------------------------------------------------------
// 64x128 MFMA core: 4 waves of 32x64 (acc[2][4]), single-buffered LDS,
// K=256 in 8 steps.
// ---------------------------------------------------------------------------
template<bool A_BF16>
__device__ __forceinline__ void mfma_core64(
    const void* __restrict__ Av, int lda, const bf16* __restrict__ Wt,
    int row0, int bn0, int M, bf16* As, bf16* Bs, f32x4 (&acc)[2][4])
{
    const int tid = threadIdx.x;
    const int lane = tid & 63;
    const int wv = tid >> 6;
    const int wm = (wv & 1) * 32, wn = (wv >> 1) * 64;
    const int l15 = lane & 15, l4 = lane >> 4;

    const int sr = tid >> 2;            // 0..63 (A row; B rows sr and sr+64)
    const int ss = tid & 3;             // 16B slot
    const int ga = min(row0 + sr, M - 1);

#pragma unroll
    for (int m = 0; m < 2; ++m)
#pragma unroll
        for (int n = 0; n < 4; ++n) { acc[m][n][0]=0.f; acc[m][n][1]=0.f; acc[m][n][2]=0.f; acc[m][n][3]=0.f; }

    for (int k0 = 0; k0 < 256; k0 += 32) {
        __syncthreads();
        {   // A tile [64][32]
            bf16 tmp[8];
            if constexpr (A_BF16) {
                *(uint4*)tmp = *(const uint4*)((const bf16*)Av + (size_t)ga * lda + k0 + ss * 8);
            } else {
                const float* ap = (const float*)Av + (size_t)ga * lda + k0 + ss * 8;
                f32x4 v0 = *(const f32x4*)ap;
                f32x4 v1 = *(const f32x4*)(ap + 4);
#pragma unroll
                for (int j = 0; j < 4; ++j) { tmp[j] = __float2bfloat16(v0[j]); tmp[4+j] = __float2bfloat16(v1[j]); }
            }
            *(uint4*)&As[sr * LDT + ss * 8] = *(const uint4*)tmp;
        }
        // B tile [128][32]
        *(uint4*)&Bs[sr * LDT + ss * 8] =
            *(const uint4*)(Wt + (size_t)(bn0 + sr) * 256 + k0 + ss * 8);
        *(uint4*)&Bs[(sr + 64) * LDT + ss * 8] =
            *(const uint4*)(Wt + (size_t)(bn0 + sr + 64) * 256 + k0 + ss * 8);
        __syncthreads();

        bf16x8 af[2], bfr[4];
#pragma unroll
        for (int m = 0; m < 2; ++m)
            af[m] = *(const bf16x8*)&As[(wm + m * 16 + l15) * LDT + l4 * 8];
#pragma unroll
        for (int n = 0; n < 4; ++n)
            bfr[n] = *(const bf16x8*)&Bs[(wn + n * 16 + l15) * LDT + l4 * 8];
#pragma unroll
        for (int m = 0; m < 2; ++m)
#pragma unroll
            for (int n = 0; n < 4; ++n)
                acc[m][n] = __builtin_amdgcn_mfma_f32_16x16x32_bf16(af[m], bfr[n], acc[m][n], 0, 0, 0);
    }
}

// ---------------------------------------------------------------------------
// Fused producer GEMM with VECTORIZED epilogue: acc tile staged to LDS
// (stride 132 elems, bank-safe), then each thread stores one contiguous
// 64B chunk (4x uint4) instead of ~48 scalar 2B stores.
// ---------------------------------------------------------------------------
__global__ __launch_bounds__(256) void gemm_producer(
    const float* __restrict__ query, const float* __restrict__ value,
    const bf16* __restrict__ Wt_cat, const bf16* __restrict__ Wt_vp,
    const float* __restrict__ bcat, const float* __restrict__ bvp,
    bf16* __restrict__ offawl, _Float16* __restrict__ vproj)
{
    __shared__ char smem[16896];    // K-loop: As 5120 + Bs 10240; epi: 64*132*2
    bf16* As = (bf16*)smem;
    bf16* Bs = (bf16*)(smem + 5120);

    constexpr int NWG = GX * 5;                 // 3475
    constexpr int QXW = NWG / 8, RXW = NWG % 8; // 434, 3
    int orig = blockIdx.x;
    int xcd = orig & 7, seq = orig >> 3;
    int swz = (xcd < RXW ? xcd * (QXW + 1) : RXW * (QXW + 1) + (xcd - RXW) * QXW) + seq;
    int slice = swz % 5;
    int row0 = (swz / 5) * BM;

    const bool isOff = slice < 3;
    const void* A = isOff ? (const void*)query : (const void*)value;
    const bf16* Wt = isOff ? Wt_cat : Wt_vp;
    const float* bias = isOff ? bcat : bvp;
    int bn0 = isOff ? slice * 128 : (slice - 3) * 128;

    f32x4 acc[2][4];
    mfma_core64<false>(A, 256, Wt, row0, bn0, MROWS, As, Bs, acc);

    const int tid = threadIdx.x;
    const int lane = tid & 63;
    const int wv = tid >> 6;
    const int wm = (wv & 1) * 32, wn = (wv >> 1) * 64;
    const int l15 = lane & 15, l4 = lane >> 4;

    __syncthreads();   // done reading K-loop LDS; reuse for epilogue
    if (isOff) {
        bf16* sE = (bf16*)smem;        // [64][132]
#pragma unroll
        for (int m = 0; m < 2; ++m)
#pragma unroll
            for (int n = 0; n < 4; ++n) {
                int col = wn + n * 16 + l15;
                float bb = bias[bn0 + col];
#pragma unroll
                for (int j = 0; j < 4; ++j) {
                    int lr = wm + m * 16 + l4 * 4 + j;
                    sE[lr * 132 + col] = __float2bfloat16(acc[m][n][j] + bb);
                }
            }
        __syncthreads();
        int row = tid >> 2, cs = (tid & 3) * 32;
        int r = row0 + row;
        if (r < MROWS) {
            bf16* dst = offawl + (size_t)r * 384 + bn0 + cs;
            const bf16* src = sE + row * 132 + cs;
#pragma unroll
            for (int t = 0; t < 4; ++t)
                *(uint4*)(dst + t * 8) = *(const uint4*)(src + t * 8);
        }
    } else {
        _Float16* sE = (_Float16*)smem;  // [64][132]
#pragma unroll
        for (int m = 0; m < 2; ++m)
#pragma unroll
            for (int n = 0; n < 4; ++n) {
                int col = wn + n * 16 + l15;
                float bb = bias[bn0 + col];
#pragma unroll
                for (int j = 0; j < 4; ++j) {
                    int lr = wm + m * 16 + l4 * 4 + j;
                    sE[lr * 132 + col] = (_Float16)(acc[m][n][j] + bb);
                }
            }
        __syncthreads();
        int row = tid >> 2, hh4 = tid & 3;
        int r = row0 + row;
        if (r < MROWS) {
            int b2 = (r >= NQ) ? 1 : 0;
            int pb = pad_base_idx(r - b2 * NQ);
            int hg = (bn0 >> 5) + hh4;      // global head 0..7
            _Float16* dst = vproj + ((size_t)(hg * 2 + b2) * PTOT + pb) * 32;
            const _Float16* src = sE + row * 132 + hh4 * 32;
#pragma unroll
            for (int t = 0; t < 4; ++t)
                *(uint4*)(dst + t * 8) = *(const uint4*)(src + t * 8);
        }
    }
}

// ---------------------------------------------------------------------------
// Output GEMM: out = msda(bf16, ld 384) @ W_op^T + b_op + query.
// ---------------------------------------------------------------------------
__global__ __launch_bounds__(256) void gemm_out(
    const bf16* __restrict__ msda, const bf16* __restrict__ Wt_op,
    const float* __restrict__ b_op, const float* __restrict__ query,
    float* __restrict__ out)
{
    __shared__ bf16 As[BM * LDT];
    __shared__ bf16 Bs[128 * LDT];

    constexpr int NWG = GX * 2;                 // 1390
    constexpr int QXW = NWG / 8, RXW = NWG % 8; // 173, 6
    int orig = blockIdx.x;
    int xcd = orig & 7, seq = orig >> 3;
    int swz = (xcd < RXW ? xcd * (QXW + 1) : RXW * (QXW + 1) + (xcd - RXW) * QXW) + seq;
    int bn0 = (swz & 1) * 128;
    int row0 = (swz >> 1) * BM;

    f32x4 acc[2][4];
    mfma_core64<true>(msda, 384, Wt_op, row0, bn0, MROWS, As, Bs, acc);

    const int lane = threadIdx.x & 63;
    const int wv = threadIdx.x >> 6;
    const int wm = (wv & 1) * 32, wn = (wv >> 1) * 64;
    const int l15 = lane & 15, l4 = lane >> 4;

#pragma unroll
    for (int m = 0; m < 2; ++m)
#pragma unroll
        for (int j = 0; j < 4; ++j) {
            int r = row0 + wm + m * 16 + l4 * 4 + j;
            if (r < MROWS) {
#pragma unroll
                for (int n = 0; n < 4; ++n) {
                    int fcol = bn0 + wn + n * 16 + l15;
                    out[(size_t)r * 256 + fcol] =
                        acc[m][n][j] + b_op[fcol] + query[(size_t)r * 256 + fcol];
                }
            }
        }
}

// ---------------------------------------------------------------------------
// MSDA sampling v18 (R18 winner, unchanged): head = blockIdx&7 -> XCD
// affinity; per-XCD L2 holds only its head's 3.04 MB vproj slab.
// ---------------------------------------------------------------------------
__device__ inline f32x2 bfpair(unsigned u) {
    f32x2 r;
    r.x = __uint_as_float(u << 16);
    r.y = __uint_as_float(u & 0xffff0000u);
    return r;
}

__global__ __launch_bounds__(256)
__attribute__((amdgpu_waves_per_eu(2, 4)))
void msda_sample18(
    const _Float16* __restrict__ vproj,  // [head][batch][ppix][32] fp16
    const bf16* __restrict__ offawl,     // [MROWS][384] bf16
    const float* __restrict__ refp,
    bf16* __restrict__ msda_out)         // aliases offawl rows (stride 384)
{
    __shared__ uint2 sOff[32][8];        // per-query 64B off head-slice
    __shared__ uint2 sAwl[32][4];        // per-query 32B awl head-slice
    __shared__ float sRef[32][8];

    const int tid = threadIdx.x;
    const int head = blockIdx.x & 7;         // == XCD under round-robin dispatch
    const int qbase = (blockIdx.x >> 3) * 32;

    {   // stage 32 queries' head-slices
        int row = tid >> 3, e = tid & 7;
        int grow = min(qbase + row, MROWS - 1);
        sOff[row][e] = *((const uint2*)(offawl + (size_t)grow * 384 + head * 32) + e);
        sRef[row][e] = refp[(size_t)grow * 8 + e];
        if (tid < 128) {
            int rowa = tid >> 2, ea = tid & 3;
            int growa = min(qbase + rowa, MROWS - 1);
            sAwl[rowa][ea] = *((const uint2*)(offawl + (size_t)growa * 384 + 256 + head * 16) + ea);
        }
    }
    __syncthreads();

    const int w = tid >> 6;       // wave 0..3
    const int lane = tid & 63;
    const int ql = lane >> 3;     // local query within wave
    const int s = lane & 7;
    const int sx = s >> 2;        // x-corner side (consumer role)
    const int c16 = s & 3;        // 16B channel chunk (consumer role)
    const int lq = w * 8 + ql;    // local query within block (0..31)
    int q = qbase + lq;
    const bool alive = q < MROWS;
    if (!alive) q = MROWS - 1;
    const int b = (q >= NQ) ? 1 : 0;

    // ---- cooperative softmax: 2 logits per lane (taps 2s, 2s+1) ----
    float aw0, aw1;
    {
        unsigned lgu = ((const unsigned*)&sAwl[lq][0])[s];
        f32x2 lg = bfpair(lgu);
        float m = fmaxf(lg.x, lg.y);
        m = fmaxf(m, __shfl_xor(m, 1));
        m = fmaxf(m, __shfl_xor(m, 2));
        m = fmaxf(m, __shfl_xor(m, 4));
        float e0 = __expf(lg.x - m), e1 = __expf(lg.y - m);
        float ssum = e0 + e1;
        ssum += __shfl_xor(ssum, 1);
        ssum += __shfl_xor(ssum, 2);
        ssum += __shfl_xor(ssum, 4);
        float inv = 1.f / ssum;
        aw0 = e0 * inv;
        aw1 = e1 * inv;
    }

    // ---- owner geometry for taps 2s, 2s+1 (level s>>1) ----
    int rpix0, rpix1;
    int rw00, rw10, rw01, rw11;   // rwXY: tap Y, x-side X weights (f16x2 bits)
    {
        const int lo = s >> 1;
        const int Wl  = (lo == 0) ? 167 : (lo == 1) ? 84 : (lo == 2) ? 42 : 21;
        const int Hl  = (lo == 0) ? 100 : (lo == 1) ? 50 : (lo == 2) ? 25 : 13;
        const int Wpl = (lo == 0) ? 170 : (lo == 1) ? 87 : (lo == 2) ? 45 : 24;
        const float xb = sRef[lq][lo * 2 + 0] * (float)Wl + 0.5f;
        const float yb = sRef[lq][lo * 2 + 1] * (float)Hl + 0.5f;
        uint2 ou = sOff[lq][s];            // taps 2s, 2s+1 offset pairs
        unsigned ouv[2] = {ou.x, ou.y};
        float awv[2] = {aw0, aw1};
        int pixv[2]; int w0v[2], w1v[2];
#pragma unroll
        for (int k = 0; k < 2; ++k) {
            f32x2 o2 = bfpair(ouv[k]);
            float x = fminf(fmaxf(xb + o2.x, 0.f), (float)(Wl + 1));
            float y = fminf(fmaxf(yb + o2.y, 0.f), (float)(Hl + 1));
            float x0f = floorf(x), y0f = floorf(y);
            float lx = x - x0f, ly = y - y0f;
            float a = awv[k];
            float wy0 = (1.f - ly) * a, wy1 = ly * a;
            float wx0 = 1.f - lx;
            pixv[k] = ((int)y0f * Wpl + (int)x0f) * 32;
            w0v[k] = (int)__builtin_bit_cast(unsigned,
                        f16x2{(_Float16)(wx0 * wy0), (_Float16)(wx0 * wy1)});
            w1v[k] = (int)__builtin_bit_cast(unsigned,
                        f16x2{(_Float16)(lx * wy0), (_Float16)(lx * wy1)});
        }
        rpix0 = pixv[0]; rw00 = w0v[0]; rw10 = w1v[0];
        rpix1 = pixv[1]; rw01 = w0v[1]; rw11 = w1v[1];
    }

    // ---- consumer: gather + accumulate ----
    const int srcbase = lane & 56;
    f16x2 acc0 = {0, 0}, acc1 = {0, 0}, acc2 = {0, 0}, acc3 = {0, 0};

#pragma unroll
    for (int l = 0; l < 4; ++l) {
        const int Wp = PLW[l];
        const _Float16* vl = vproj + ((size_t)(head * 2 + b) * PTOT + PLSTART[l]) * 32
                             + sx * 32 + c16 * 8;

        const _Float16* pr[4][2];
        f16x2 hw0[4], hw1[4];
#pragma unroll
        for (int p = 0; p < 4; ++p) {
            const int t = l * 4 + p;          // compile-time
            const int src = srcbase | (t >> 1);
            int pix, wa, wb;
            if (t & 1) {                       // compile-time parity
                pix = __shfl(rpix1, src);
                wa  = __shfl(rw01, src);
                wb  = __shfl(rw11, src);
            } else {
                pix = __shfl(rpix0, src);
                wa  = __shfl(rw00, src);
                wb  = __shfl(rw10, src);
            }
            f16x2 wv = __builtin_bit_cast(f16x2, (unsigned)(sx ? wb : wa));
            hw0[p] = f16x2{wv[0], wv[0]};
            hw1[p] = f16x2{wv[1], wv[1]};
            pr[p][0] = vl + pix;
            pr[p][1] = pr[p][0] + Wp * 32;
        }

        uint4 c[4][2];
#pragma unroll
        for (int p = 0; p < 4; ++p) {
            c[p][0] = *(const uint4*)pr[p][0];
            c[p][1] = *(const uint4*)pr[p][1];
        }

#pragma unroll
        for (int p = 0; p < 4; ++p) {
            acc0 += __builtin_bit_cast(f16x2, c[p][0].x) * hw0[p];
            acc1 += __builtin_bit_cast(f16x2, c[p][0].y) * hw0[p];
            acc2 += __builtin_bit_cast(f16x2, c[p][0].z) * hw0[p];
            acc3 += __builtin_bit_cast(f16x2, c[p][0].w) * hw0[p];
            acc0 += __builtin_bit_cast(f16x2, c[p][1].x) * hw1[p];
            acc1 += __builtin_bit_cast(f16x2, c[p][1].y) * hw1[p];
            acc2 += __builtin_bit_cast(f16x2, c[p][1].z) * hw1[p];
            acc3 += __builtin_bit_cast(f16x2, c[p][1].w) * hw1[p];
        }
    }

    // combine x0/x1 partial sums across lane pairs (s ^ 4)
    {
        unsigned u0 = __builtin_bit_cast(unsigned, acc0);
        unsigned u1 = __builtin_bit_cast(unsigned, acc1);
        unsigned u2 = __builtin_bit_cast(unsigned, acc2);
        unsigned u3 = __builtin_bit_cast(unsigned, acc3);
        acc0 += __builtin_bit_cast(f16x2, __shfl_xor((int)u0, 4));
        acc1 += __builtin_bit_cast(f16x2, __shfl_xor((int)u1, 4));
        acc2 += __builtin_bit_cast(f16x2, __shfl_xor((int)u2, 4));
        acc3 += __builtin_bit_cast(f16x2, __shfl_xor((int)u3, 4));
    }

    if (alive && sx == 0) {
        bf16 ob[8];
        ob[0] = __float2bfloat16((float)acc0[0]);
        ob[1] = __float2bfloat16((float)acc0[1]);
        ob[2] = __float2bfloat16((float)acc1[0]);
        ob[3] = __float2bfloat16((float)acc1[1]);
        ob[4] = __float2bfloat16((float)acc2[0]);
        ob[5] = __float2bfloat16((float)acc2[1]);
        ob[6] = __float2bfloat16((float)acc3[0]);
        ob[7] = __float2bfloat16((float)acc3[1]);
        *(uint4*)(msda_out + (size_t)q * 384 + head * 32 + c16 * 8) = *(const uint4*)ob;
    }
}

// ---------------------------------------------------------------------------
extern "C" void kernel_launch(void* const* d_in, const int* in_sizes, int n_in,
                              void* d_out, int out_size, void* d_ws, size_t ws_size,
                              hipStream_t stream) {
    const float* query = (const float*)d_in[0];
    const float* value = (const float*)d_in[1];
    const float* refp  = (const float*)d_in[2];
    const float* W_so  = (const float*)d_in[3];
    const float* b_so  = (const float*)d_in[4];
    const float* W_aw  = (const float*)d_in[5];
    const float* b_aw  = (const float*)d_in[6];
    const float* W_vp  = (const float*)d_in[7];
    const float* b_vp  = (const float*)d_in[8];
    const float* W_op  = (const float*)d_in[9];
    const float* b_op  = (const float*)d_in[10];
    float* out = (float*)d_out;

    // Workspace:
    //   offawl : bf16 MROWS*384 (34.1 MB) [off|awl]; msda aliased over rows
    //   vproj  : fp16 16*PTOT*32 (24.3 MB) head-major zero-padded layout
    //   weights: Wt_cat 384*256, Wt_vp/Wt_op 256*256 bf16, bcat 384 f32
    bf16*     d_offawl = (bf16*)d_ws;
    _Float16* d_vproj  = (_Float16*)(d_offawl + (size_t)MROWS * 384);
    bf16*     d_wtcat  = (bf16*)(d_vproj + (size_t)16 * PTOT * 32);
    bf16*     d_wtvp   = d_wtcat + 384 * 256;
    bf16*     d_wtop   = d_wtvp + 256 * 256;
    float*    d_bcat   = (float*)(d_wtop + 256 * 256);

    prep_weights<<<384, 256, 0, stream>>>(W_vp, W_so, W_aw, W_op, b_so, b_aw,
                                          d_wtvp, d_wtcat, d_wtop, d_bcat);
    hipMemsetAsync(d_vproj, 0, (size_t)16 * PTOT * 32 * sizeof(_Float16), stream);

    gemm_producer<<<GX * 5, 256, 0, stream>>>(
        query, value, d_wtcat, d_wtvp, d_bcat, b_vp, d_offawl, d_vproj);

    // 8 heads x 1389 query-chunks; head = blockIdx&7 -> XCD affinity
    msda_sample18<<<8 * ((MROWS + 31) / 32), 256, 0, stream>>>(
        d_vproj, d_offawl, refp, d_offawl);

    gemm_out<<<GX * 2, 256, 0, stream>>>(d_offawl, d_wtop, b_op, query, out);
}

// Round 23
// 137.140 us; speedup vs baseline: 1.0673x; 1.0673x over previous
//
#include <hip/hip_runtime.h>
#include <hip/hip_bf16.h>
#include <math.h>

typedef __hip_bfloat16 bf16;
using f32x4  = __attribute__((ext_vector_type(4))) float;
using f32x2  = __attribute__((ext_vector_type(2))) float;
using bf16x8 = __attribute__((ext_vector_type(8))) short;
using f16x2  = __attribute__((ext_vector_type(2))) _Float16;

constexpr int BS = 2, NQ = 22223, MROWS = 44446;
constexpr int LH[4] = {100, 50, 25, 13};
constexpr int LW[4] = {167, 84, 42, 21};
constexpr int LSTART[4] = {0, 16700, 20900, 21950};
// Padded levels: +1 left/top, +2 right/bottom (Wp=W+3, Hp=H+3)
constexpr int PLW[4] = {170, 87, 45, 24};
constexpr int PLSTART[4] = {0, 17510, 22121, 23381};
constexpr int PTOT = 23765;

constexpr int BM = 64;                // rows per block
constexpr int LDT = 40;               // LDS row stride (bf16): 80B
constexpr int GX = (MROWS + BM - 1) / BM;   // 695

// ---------------------------------------------------------------------------
__global__ __launch_bounds__(256) void prep_weights(
    const float* __restrict__ W_vp, const float* __restrict__ W_so,
    const float* __restrict__ W_aw, const float* __restrict__ W_op,
    const float* __restrict__ b_so, const float* __restrict__ b_aw,
    bf16* __restrict__ Wt_vp, bf16* __restrict__ Wt_cat,
    bf16* __restrict__ Wt_op, float* __restrict__ bcat)
{
    int i = blockIdx.x * 256 + threadIdx.x;
    if (i < 256 * 256) {
        int n = i >> 8, k = i & 255;
        Wt_vp[i] = __float2bfloat16(W_vp[k * 256 + n]);
        Wt_op[i] = __float2bfloat16(W_op[k * 256 + n]);
    }
    if (i < 384 * 256) {
        int n = i >> 8, k = i & 255;
        float v = (n < 256) ? W_so[k * 256 + n] : W_aw[k * 128 + (n - 256)];
        Wt_cat[i] = __float2bfloat16(v);
    }
    if (i < 384) bcat[i] = (i < 256) ? b_so[i] : b_aw[i - 256];
}

// Map batch-local value pixel -> level-local padded pixel index (+1,+1 offset)
__device__ inline int pad_base_idx(int pix) {
    if (pix < LSTART[1])      { int y = pix / 167;                  int x = pix - y * 167;                return PLSTART[0] + (y + 1) * 170 + (x + 1); }
    else if (pix < LSTART[2]) { int rel = pix - LSTART[1]; int y = rel / 84; int x = rel - y * 84;        return PLSTART[1] + (y + 1) * 87  + (x + 1); }
    else if (pix < LSTART[3]) { int rel = pix - LSTART[2]; int y = rel / 42; int x = rel - y * 42;        return PLSTART[2] + (y + 1) * 45  + (x + 1); }
    else                      { int rel = pix - LSTART[3]; int y = rel / 21; int x = rel - y * 21;        return PLSTART[3] + (y + 1) * 24  + (x + 1); }
}

// ---------------------------------------------------------------------------
// 64x128 MFMA core: 4 waves of 32x64 (acc[2][4]), single-buffered LDS,
// K=256 in 8 steps.
// ---------------------------------------------------------------------------
template<bool A_BF16>
__device__ __forceinline__ void mfma_core64(
    const void* __restrict__ Av, int lda, const bf16* __restrict__ Wt,
    int row0, int bn0, int M, bf16* As, bf16* Bs, f32x4 (&acc)[2][4])
{
    const int tid = threadIdx.x;
    const int lane = tid & 63;
    const int wv = tid >> 6;
    const int wm = (wv & 1) * 32, wn = (wv >> 1) * 64;
    const int l15 = lane & 15, l4 = lane >> 4;

    const int sr = tid >> 2;            // 0..63 (A row; B rows sr and sr+64)
    const int ss = tid & 3;             // 16B slot
    const int ga = min(row0 + sr, M - 1);

#pragma unroll
    for (int m = 0; m < 2; ++m)
#pragma unroll
        for (int n = 0; n < 4; ++n) { acc[m][n][0]=0.f; acc[m][n][1]=0.f; acc[m][n][2]=0.f; acc[m][n][3]=0.f; }

    for (int k0 = 0; k0 < 256; k0 += 32) {
        __syncthreads();
        {   // A tile [64][32]
            bf16 tmp[8];
            if constexpr (A_BF16) {
                *(uint4*)tmp = *(const uint4*)((const bf16*)Av + (size_t)ga * lda + k0 + ss * 8);
            } else {
                const float* ap = (const float*)Av + (size_t)ga * lda + k0 + ss * 8;
                f32x4 v0 = *(const f32x4*)ap;
                f32x4 v1 = *(const f32x4*)(ap + 4);
#pragma unroll
                for (int j = 0; j < 4; ++j) { tmp[j] = __float2bfloat16(v0[j]); tmp[4+j] = __float2bfloat16(v1[j]); }
            }
            *(uint4*)&As[sr * LDT + ss * 8] = *(const uint4*)tmp;
        }
        // B tile [128][32]
        *(uint4*)&Bs[sr * LDT + ss * 8] =
            *(const uint4*)(Wt + (size_t)(bn0 + sr) * 256 + k0 + ss * 8);
        *(uint4*)&Bs[(sr + 64) * LDT + ss * 8] =
            *(const uint4*)(Wt + (size_t)(bn0 + sr + 64) * 256 + k0 + ss * 8);
        __syncthreads();

        bf16x8 af[2], bfr[4];
#pragma unroll
        for (int m = 0; m < 2; ++m)
            af[m] = *(const bf16x8*)&As[(wm + m * 16 + l15) * LDT + l4 * 8];
#pragma unroll
        for (int n = 0; n < 4; ++n)
            bfr[n] = *(const bf16x8*)&Bs[(wn + n * 16 + l15) * LDT + l4 * 8];
#pragma unroll
        for (int m = 0; m < 2; ++m)
#pragma unroll
            for (int n = 0; n < 4; ++n)
                acc[m][n] = __builtin_amdgcn_mfma_f32_16x16x32_bf16(af[m], bfr[n], acc[m][n], 0, 0, 0);
    }
}

// ---------------------------------------------------------------------------
// Fused producer GEMM: 5 N-slices per 64-row panel (3 offawl bf16 + 2 vproj
// fp16 head-major scatter), slice-fastest + bijective XCD swizzle.
// ---------------------------------------------------------------------------
__global__ __launch_bounds__(256) void gemm_producer(
    const float* __restrict__ query, const float* __restrict__ value,
    const bf16* __restrict__ Wt_cat, const bf16* __restrict__ Wt_vp,
    const float* __restrict__ bcat, const float* __restrict__ bvp,
    bf16* __restrict__ offawl, _Float16* __restrict__ vproj)
{
    __shared__ bf16 As[BM * LDT];
    __shared__ bf16 Bs[128 * LDT];

    constexpr int NWG = GX * 5;                 // 3475
    constexpr int QXW = NWG / 8, RXW = NWG % 8; // 434, 3
    int orig = blockIdx.x;
    int xcd = orig & 7, seq = orig >> 3;
    int swz = (xcd < RXW ? xcd * (QXW + 1) : RXW * (QXW + 1) + (xcd - RXW) * QXW) + seq;
    int slice = swz % 5;
    int row0 = (swz / 5) * BM;

    const bool isOff = slice < 3;
    const void* A = isOff ? (const void*)query : (const void*)value;
    const bf16* Wt = isOff ? Wt_cat : Wt_vp;
    const float* bias = isOff ? bcat : bvp;
    int bn0 = isOff ? slice * 128 : (slice - 3) * 128;

    f32x4 acc[2][4];
    mfma_core64<false>(A, 256, Wt, row0, bn0, MROWS, As, Bs, acc);

    const int lane = threadIdx.x & 63;
    const int wv = threadIdx.x >> 6;
    const int wm = (wv & 1) * 32, wn = (wv >> 1) * 64;
    const int l15 = lane & 15, l4 = lane >> 4;

    if (isOff) {
#pragma unroll
        for (int m = 0; m < 2; ++m)
#pragma unroll
            for (int j = 0; j < 4; ++j) {
                int r = row0 + wm + m * 16 + l4 * 4 + j;
                if (r < MROWS) {
                    bf16* orow = offawl + (size_t)r * 384;
#pragma unroll
                    for (int n = 0; n < 4; ++n) {
                        int fcol = bn0 + wn + n * 16 + l15;
                        orow[fcol] = __float2bfloat16(acc[m][n][j] + bias[fcol]);
                    }
                }
            }
    } else {
#pragma unroll
        for (int m = 0; m < 2; ++m)
#pragma unroll
            for (int j = 0; j < 4; ++j) {
                int r = row0 + wm + m * 16 + l4 * 4 + j;
                if (r < MROWS) {
                    int bb = (r >= NQ) ? 1 : 0;
                    int pb = pad_base_idx(r - bb * NQ);
#pragma unroll
                    for (int n = 0; n < 4; ++n) {
                        int fcol = bn0 + wn + n * 16 + l15;
                        int hh = fcol >> 5, cc = fcol & 31;
                        vproj[((size_t)(hh * 2 + bb) * PTOT + pb) * 32 + cc] =
                            (_Float16)(acc[m][n][j] + bias[fcol]);
                    }
                }
            }
    }
}

// ---------------------------------------------------------------------------
// Output GEMM: out = msda(bf16, ld 384) @ W_op^T + b_op + query.
// ---------------------------------------------------------------------------
__global__ __launch_bounds__(256) void gemm_out(
    const bf16* __restrict__ msda, const bf16* __restrict__ Wt_op,
    const float* __restrict__ b_op, const float* __restrict__ query,
    float* __restrict__ out)
{
    __shared__ bf16 As[BM * LDT];
    __shared__ bf16 Bs[128 * LDT];

    constexpr int NWG = GX * 2;                 // 1390
    constexpr int QXW = NWG / 8, RXW = NWG % 8; // 173, 6
    int orig = blockIdx.x;
    int xcd = orig & 7, seq = orig >> 3;
    int swz = (xcd < RXW ? xcd * (QXW + 1) : RXW * (QXW + 1) + (xcd - RXW) * QXW) + seq;
    int bn0 = (swz & 1) * 128;
    int row0 = (swz >> 1) * BM;

    f32x4 acc[2][4];
    mfma_core64<true>(msda, 384, Wt_op, row0, bn0, MROWS, As, Bs, acc);

    const int lane = threadIdx.x & 63;
    const int wv = threadIdx.x >> 6;
    const int wm = (wv & 1) * 32, wn = (wv >> 1) * 64;
    const int l15 = lane & 15, l4 = lane >> 4;

#pragma unroll
    for (int m = 0; m < 2; ++m)
#pragma unroll
        for (int j = 0; j < 4; ++j) {
            int r = row0 + wm + m * 16 + l4 * 4 + j;
            if (r < MROWS) {
#pragma unroll
                for (int n = 0; n < 4; ++n) {
                    int fcol = bn0 + wn + n * 16 + l15;
                    out[(size_t)r * 256 + fcol] =
                        acc[m][n][j] + b_op[fcol] + query[(size_t)r * 256 + fcol];
                }
            }
        }
}

// ---------------------------------------------------------------------------
// MSDA sampling v18 math with waves_per_eu(4,4): same 128-VGPR codegen cap
// (max=4) so the 52-VGPR batched codegen is preserved; min=4 raises the
// runtime residency target from the measured ~3 waves/EU toward 4.
// head = blockIdx&7 -> XCD affinity (per-XCD L2 holds one head's slab).
// ---------------------------------------------------------------------------
__device__ inline f32x2 bfpair(unsigned u) {
    f32x2 r;
    r.x = __uint_as_float(u << 16);
    r.y = __uint_as_float(u & 0xffff0000u);
    return r;
}

__global__ __launch_bounds__(256)
__attribute__((amdgpu_waves_per_eu(4, 4)))
void msda_sample18(
    const _Float16* __restrict__ vproj,  // [head][batch][ppix][32] fp16
    const bf16* __restrict__ offawl,     // [MROWS][384] bf16
    const float* __restrict__ refp,
    bf16* __restrict__ msda_out)         // aliases offawl rows (stride 384)
{
    __shared__ uint2 sOff[32][8];        // per-query 64B off head-slice
    __shared__ uint2 sAwl[32][4];        // per-query 32B awl head-slice
    __shared__ float sRef[32][8];

    const int tid = threadIdx.x;
    const int head = blockIdx.x & 7;         // == XCD under round-robin dispatch
    const int qbase = (blockIdx.x >> 3) * 32;

    {   // stage 32 queries' head-slices
        int row = tid >> 3, e = tid & 7;
        int grow = min(qbase + row, MROWS - 1);
        sOff[row][e] = *((const uint2*)(offawl + (size_t)grow * 384 + head * 32) + e);
        sRef[row][e] = refp[(size_t)grow * 8 + e];
        if (tid < 128) {
            int rowa = tid >> 2, ea = tid & 3;
            int growa = min(qbase + rowa, MROWS - 1);
            sAwl[rowa][ea] = *((const uint2*)(offawl + (size_t)growa * 384 + 256 + head * 16) + ea);
        }
    }
    __syncthreads();

    const int w = tid >> 6;       // wave 0..3
    const int lane = tid & 63;
    const int ql = lane >> 3;     // local query within wave
    const int s = lane & 7;
    const int sx = s >> 2;        // x-corner side (consumer role)
    const int c16 = s & 3;        // 16B channel chunk (consumer role)
    const int lq = w * 8 + ql;    // local query within block (0..31)
    int q = qbase + lq;
    const bool alive = q < MROWS;
    if (!alive) q = MROWS - 1;
    const int b = (q >= NQ) ? 1 : 0;

    // ---- cooperative softmax: 2 logits per lane (taps 2s, 2s+1) ----
    float aw0, aw1;
    {
        unsigned lgu = ((const unsigned*)&sAwl[lq][0])[s];
        f32x2 lg = bfpair(lgu);
        float m = fmaxf(lg.x, lg.y);
        m = fmaxf(m, __shfl_xor(m, 1));
        m = fmaxf(m, __shfl_xor(m, 2));
        m = fmaxf(m, __shfl_xor(m, 4));
        float e0 = __expf(lg.x - m), e1 = __expf(lg.y - m);
        float ssum = e0 + e1;
        ssum += __shfl_xor(ssum, 1);
        ssum += __shfl_xor(ssum, 2);
        ssum += __shfl_xor(ssum, 4);
        float inv = 1.f / ssum;
        aw0 = e0 * inv;
        aw1 = e1 * inv;
    }

    // ---- owner geometry for taps 2s, 2s+1 (level s>>1) ----
    int rpix0, rpix1;
    int rw00, rw10, rw01, rw11;   // rwXY: tap Y, x-side X weights (f16x2 bits)
    {
        const int lo = s >> 1;
        const int Wl  = (lo == 0) ? 167 : (lo == 1) ? 84 : (lo == 2) ? 42 : 21;
        const int Hl  = (lo == 0) ? 100 : (lo == 1) ? 50 : (lo == 2) ? 25 : 13;
        const int Wpl = (lo == 0) ? 170 : (lo == 1) ? 87 : (lo == 2) ? 45 : 24;
        const float xb = sRef[lq][lo * 2 + 0] * (float)Wl + 0.5f;
        const float yb = sRef[lq][lo * 2 + 1] * (float)Hl + 0.5f;
        uint2 ou = sOff[lq][s];            // taps 2s, 2s+1 offset pairs
        unsigned ouv[2] = {ou.x, ou.y};
        float awv[2] = {aw0, aw1};
        int pixv[2]; int w0v[2], w1v[2];
#pragma unroll
        for (int k = 0; k < 2; ++k) {
            f32x2 o2 = bfpair(ouv[k]);
            float x = fminf(fmaxf(xb + o2.x, 0.f), (float)(Wl + 1));
            float y = fminf(fmaxf(yb + o2.y, 0.f), (float)(Hl + 1));
            float x0f = floorf(x), y0f = floorf(y);
            float lx = x - x0f, ly = y - y0f;
            float a = awv[k];
            float wy0 = (1.f - ly) * a, wy1 = ly * a;
            float wx0 = 1.f - lx;
            pixv[k] = ((int)y0f * Wpl + (int)x0f) * 32;
            w0v[k] = (int)__builtin_bit_cast(unsigned,
                        f16x2{(_Float16)(wx0 * wy0), (_Float16)(wx0 * wy1)});
            w1v[k] = (int)__builtin_bit_cast(unsigned,
                        f16x2{(_Float16)(lx * wy0), (_Float16)(lx * wy1)});
        }
        rpix0 = pixv[0]; rw00 = w0v[0]; rw10 = w1v[0];
        rpix1 = pixv[1]; rw01 = w0v[1]; rw11 = w1v[1];
    }

    // ---- consumer: gather + accumulate ----
    const int srcbase = lane & 56;
    f16x2 acc0 = {0, 0}, acc1 = {0, 0}, acc2 = {0, 0}, acc3 = {0, 0};

#pragma unroll
    for (int l = 0; l < 4; ++l) {
        const int Wp = PLW[l];
        const _Float16* vl = vproj + ((size_t)(head * 2 + b) * PTOT + PLSTART[l]) * 32
                             + sx * 32 + c16 * 8;

        const _Float16* pr[4][2];
        f16x2 hw0[4], hw1[4];
#pragma unroll
        for (int p = 0; p < 4; ++p) {
            const int t = l * 4 + p;          // compile-time
            const int src = srcbase | (t >> 1);
            int pix, wa, wb;
            if (t & 1) {                       // compile-time parity
                pix = __shfl(rpix1, src);
                wa  = __shfl(rw01, src);
                wb  = __shfl(rw11, src);
            } else {
                pix = __shfl(rpix0, src);
                wa  = __shfl(rw00, src);
                wb  = __shfl(rw10, src);
            }
            f16x2 wv = __builtin_bit_cast(f16x2, (unsigned)(sx ? wb : wa));
            hw0[p] = f16x2{wv[0], wv[0]};
            hw1[p] = f16x2{wv[1], wv[1]};
            pr[p][0] = vl + pix;
            pr[p][1] = pr[p][0] + Wp * 32;
        }

        uint4 c[4][2];
#pragma unroll
        for (int p = 0; p < 4; ++p) {
            c[p][0] = *(const uint4*)pr[p][0];
            c[p][1] = *(const uint4*)pr[p][1];
        }

#pragma unroll
        for (int p = 0; p < 4; ++p) {
            acc0 += __builtin_bit_cast(f16x2, c[p][0].x) * hw0[p];
            acc1 += __builtin_bit_cast(f16x2, c[p][0].y) * hw0[p];
            acc2 += __builtin_bit_cast(f16x2, c[p][0].z) * hw0[p];
            acc3 += __builtin_bit_cast(f16x2, c[p][0].w) * hw0[p];
            acc0 += __builtin_bit_cast(f16x2, c[p][1].x) * hw1[p];
            acc1 += __builtin_bit_cast(f16x2, c[p][1].y) * hw1[p];
            acc2 += __builtin_bit_cast(f16x2, c[p][1].z) * hw1[p];
            acc3 += __builtin_bit_cast(f16x2, c[p][1].w) * hw1[p];
        }
    }

    // combine x0/x1 partial sums across lane pairs (s ^ 4)
    {
        unsigned u0 = __builtin_bit_cast(unsigned, acc0);
        unsigned u1 = __builtin_bit_cast(unsigned, acc1);
        unsigned u2 = __builtin_bit_cast(unsigned, acc2);
        unsigned u3 = __builtin_bit_cast(unsigned, acc3);
        acc0 += __builtin_bit_cast(f16x2, __shfl_xor((int)u0, 4));
        acc1 += __builtin_bit_cast(f16x2, __shfl_xor((int)u1, 4));
        acc2 += __builtin_bit_cast(f16x2, __shfl_xor((int)u2, 4));
        acc3 += __builtin_bit_cast(f16x2, __shfl_xor((int)u3, 4));
    }

    if (alive && sx == 0) {
        bf16 ob[8];
        ob[0] = __float2bfloat16((float)acc0[0]);
        ob[1] = __float2bfloat16((float)acc0[1]);
        ob[2] = __float2bfloat16((float)acc1[0]);
        ob[3] = __float2bfloat16((float)acc1[1]);
        ob[4] = __float2bfloat16((float)acc2[0]);
        ob[5] = __float2bfloat16((float)acc2[1]);
        ob[6] = __float2bfloat16((float)acc3[0]);
        ob[7] = __float2bfloat16((float)acc3[1]);
        *(uint4*)(msda_out + (size_t)q * 384 + head * 32 + c16 * 8) = *(const uint4*)ob;
    }
}

// ---------------------------------------------------------------------------
extern "C" void kernel_launch(void* const* d_in, const int* in_sizes, int n_in,
                              void* d_out, int out_size, void* d_ws, size_t ws_size,
                              hipStream_t stream) {
    const float* query = (const float*)d_in[0];
    const float* value = (const float*)d_in[1];
    const float* refp  = (const float*)d_in[2];
    const float* W_so  = (const float*)d_in[3];
    const float* b_so  = (const float*)d_in[4];
    const float* W_aw  = (const float*)d_in[5];
    const float* b_aw  = (const float*)d_in[6];
    const float* W_vp  = (const float*)d_in[7];
    const float* b_vp  = (const float*)d_in[8];
    const float* W_op  = (const float*)d_in[9];
    const float* b_op  = (const float*)d_in[10];
    float* out = (float*)d_out;

    // Workspace:
    //   offawl : bf16 MROWS*384 (34.1 MB) [off|awl]; msda aliased over rows
    //   vproj  : fp16 16*PTOT*32 (24.3 MB) head-major zero-padded layout
    //   weights: Wt_cat 384*256, Wt_vp/Wt_op 256*256 bf16, bcat 384 f32
    bf16*     d_offawl = (bf16*)d_ws;
    _Float16* d_vproj  = (_Float16*)(d_offawl + (size_t)MROWS * 384);
    bf16*     d_wtcat  = (bf16*)(d_vproj + (size_t)16 * PTOT * 32);
    bf16*     d_wtvp   = d_wtcat + 384 * 256;
    bf16*     d_wtop   = d_wtvp + 256 * 256;
    float*    d_bcat   = (float*)(d_wtop + 256 * 256);

    prep_weights<<<384, 256, 0, stream>>>(W_vp, W_so, W_aw, W_op, b_so, b_aw,
                                          d_wtvp, d_wtcat, d_wtop, d_bcat);
    hipMemsetAsync(d_vproj, 0, (size_t)16 * PTOT * 32 * sizeof(_Float16), stream);

    gemm_producer<<<GX * 5, 256, 0, stream>>>(
        query, value, d_wtcat, d_wtvp, d_bcat, b_vp, d_offawl, d_vproj);

    // 8 heads x 1389 query-chunks; head = blockIdx&7 -> XCD affinity
    msda_sample18<<<8 * ((MROWS + 31) / 32), 256, 0, stream>>>(
        d_vproj, d_offawl, refp, d_offawl);

    gemm_out<<<GX * 2, 256, 0, stream>>>(d_offawl, d_wtop, b_op, query, out);
}

// Round 24
// 136.561 us; speedup vs baseline: 1.0718x; 1.0042x over previous
//
#include <hip/hip_runtime.h>
#include <hip/hip_bf16.h>
#include <math.h>

typedef __hip_bfloat16 bf16;
using f32x4  = __attribute__((ext_vector_type(4))) float;
using f32x2  = __attribute__((ext_vector_type(2))) float;
using bf16x8 = __attribute__((ext_vector_type(8))) short;
using f16x2  = __attribute__((ext_vector_type(2))) _Float16;

constexpr int BS = 2, NQ = 22223, MROWS = 44446;
constexpr int LH[4] = {100, 50, 25, 13};
constexpr int LW[4] = {167, 84, 42, 21};
constexpr int LSTART[4] = {0, 16700, 20900, 21950};
// Padded levels: +1 left/top, +2 right/bottom (Wp=W+3, Hp=H+3)
constexpr int PLW[4] = {170, 87, 45, 24};
constexpr int PLSTART[4] = {0, 17510, 22121, 23381};
constexpr int PTOT = 23765;

constexpr int BM = 64;                // rows per block
constexpr int LDT = 40;               // A-tile LDS row stride (bf16): 80B padded
constexpr int GX = (MROWS + BM - 1) / BM;   // 695

// ---------------------------------------------------------------------------
__global__ __launch_bounds__(256) void prep_weights(
    const float* __restrict__ W_vp, const float* __restrict__ W_so,
    const float* __restrict__ W_aw, const float* __restrict__ W_op,
    const float* __restrict__ b_so, const float* __restrict__ b_aw,
    bf16* __restrict__ Wt_vp, bf16* __restrict__ Wt_cat,
    bf16* __restrict__ Wt_op, float* __restrict__ bcat)
{
    int i = blockIdx.x * 256 + threadIdx.x;
    if (i < 256 * 256) {
        int n = i >> 8, k = i & 255;
        Wt_vp[i] = __float2bfloat16(W_vp[k * 256 + n]);
        Wt_op[i] = __float2bfloat16(W_op[k * 256 + n]);
    }
    if (i < 384 * 256) {
        int n = i >> 8, k = i & 255;
        float v = (n < 256) ? W_so[k * 256 + n] : W_aw[k * 128 + (n - 256)];
        Wt_cat[i] = __float2bfloat16(v);
    }
    if (i < 384) bcat[i] = (i < 256) ? b_so[i] : b_aw[i - 256];
}

// Map batch-local value pixel -> level-local padded pixel index (+1,+1 offset)
__device__ inline int pad_base_idx(int pix) {
    if (pix < LSTART[1])      { int y = pix / 167;                  int x = pix - y * 167;                return PLSTART[0] + (y + 1) * 170 + (x + 1); }
    else if (pix < LSTART[2]) { int rel = pix - LSTART[1]; int y = rel / 84; int x = rel - y * 84;        return PLSTART[1] + (y + 1) * 87  + (x + 1); }
    else if (pix < LSTART[3]) { int rel = pix - LSTART[2]; int y = rel / 42; int x = rel - y * 42;        return PLSTART[2] + (y + 1) * 45  + (x + 1); }
    else                      { int rel = pix - LSTART[3]; int y = rel / 21; int x = rel - y * 21;        return PLSTART[3] + (y + 1) * 24  + (x + 1); }
}

// ---------------------------------------------------------------------------
// 64x128 MFMA core: 4 waves of 32x64 (acc[2][4]).
// A: reg-staged (fp32->bf16 convert) into padded [64][40] LDS.
// B: __builtin_amdgcn_global_load_lds width=16 into LINEAR [128][32] LDS
//    (wave-uniform base + lane*16 — verified mapping: tid*16 within wave).
// ---------------------------------------------------------------------------
template<bool A_BF16>
__device__ __forceinline__ void mfma_core64(
    const void* __restrict__ Av, int lda, const bf16* __restrict__ Wt,
    int row0, int bn0, int M, bf16* As, bf16* Bs, f32x4 (&acc)[2][4])
{
    const int tid = threadIdx.x;
    const int lane = tid & 63;
    const int wv = tid >> 6;
    const int wm = (wv & 1) * 32, wn = (wv >> 1) * 64;
    const int l15 = lane & 15, l4 = lane >> 4;

    const int sr = tid >> 2;            // 0..63 (A row; B rows sr and sr+64)
    const int ss = tid & 3;             // 16B slot
    const int ga = min(row0 + sr, M - 1);

#pragma unroll
    for (int m = 0; m < 2; ++m)
#pragma unroll
        for (int n = 0; n < 4; ++n) { acc[m][n][0]=0.f; acc[m][n][1]=0.f; acc[m][n][2]=0.f; acc[m][n][3]=0.f; }

    for (int k0 = 0; k0 < 256; k0 += 32) {
        __syncthreads();
        // B tile [128][32] linear via DMA: lds byte = sr*64 + ss*16 (= tid*16)
        {
            const bf16* bp0 = Wt + (size_t)(bn0 + sr) * 256 + k0 + ss * 8;
            const bf16* bp1 = Wt + (size_t)(bn0 + sr + 64) * 256 + k0 + ss * 8;
            __builtin_amdgcn_global_load_lds((const __attribute__((address_space(1))) void*)bp0,
                (__attribute__((address_space(3))) void*)(Bs + sr * 32 + ss * 8), 16, 0, 0);
            __builtin_amdgcn_global_load_lds((const __attribute__((address_space(1))) void*)bp1,
                (__attribute__((address_space(3))) void*)(Bs + (sr + 64) * 32 + ss * 8), 16, 0, 0);
        }
        {   // A tile [64][40-padded], reg-staged (needs convert)
            bf16 tmp[8];
            if constexpr (A_BF16) {
                *(uint4*)tmp = *(const uint4*)((const bf16*)Av + (size_t)ga * lda + k0 + ss * 8);
            } else {
                const float* ap = (const float*)Av + (size_t)ga * lda + k0 + ss * 8;
                f32x4 v0 = *(const f32x4*)ap;
                f32x4 v1 = *(const f32x4*)(ap + 4);
#pragma unroll
                for (int j = 0; j < 4; ++j) { tmp[j] = __float2bfloat16(v0[j]); tmp[4+j] = __float2bfloat16(v1[j]); }
            }
            *(uint4*)&As[sr * LDT + ss * 8] = *(const uint4*)tmp;
        }
        __syncthreads();   // drains vmcnt (DMA) + lgkmcnt (ds_write)

        bf16x8 af[2], bfr[4];
#pragma unroll
        for (int m = 0; m < 2; ++m)
            af[m] = *(const bf16x8*)&As[(wm + m * 16 + l15) * LDT + l4 * 8];
#pragma unroll
        for (int n = 0; n < 4; ++n)
            bfr[n] = *(const bf16x8*)&Bs[(wn + n * 16 + l15) * 32 + l4 * 8];
#pragma unroll
        for (int m = 0; m < 2; ++m)
#pragma unroll
            for (int n = 0; n < 4; ++n)
                acc[m][n] = __builtin_amdgcn_mfma_f32_16x16x32_bf16(af[m], bfr[n], acc[m][n], 0, 0, 0);
    }
}

// ---------------------------------------------------------------------------
// Fused producer GEMM: 5 N-slices per 64-row panel (3 offawl bf16 + 2 vproj
// fp16 head-major scatter), slice-fastest + bijective XCD swizzle.
// ---------------------------------------------------------------------------
__global__ __launch_bounds__(256) void gemm_producer(
    const float* __restrict__ query, const float* __restrict__ value,
    const bf16* __restrict__ Wt_cat, const bf16* __restrict__ Wt_vp,
    const float* __restrict__ bcat, const float* __restrict__ bvp,
    bf16* __restrict__ offawl, _Float16* __restrict__ vproj)
{
    __shared__ bf16 As[BM * LDT];
    __shared__ bf16 Bs[128 * 32];

    constexpr int NWG = GX * 5;                 // 3475
    constexpr int QXW = NWG / 8, RXW = NWG % 8; // 434, 3
    int orig = blockIdx.x;
    int xcd = orig & 7, seq = orig >> 3;
    int swz = (xcd < RXW ? xcd * (QXW + 1) : RXW * (QXW + 1) + (xcd - RXW) * QXW) + seq;
    int slice = swz % 5;
    int row0 = (swz / 5) * BM;

    const bool isOff = slice < 3;
    const void* A = isOff ? (const void*)query : (const void*)value;
    const bf16* Wt = isOff ? Wt_cat : Wt_vp;
    const float* bias = isOff ? bcat : bvp;
    int bn0 = isOff ? slice * 128 : (slice - 3) * 128;

    f32x4 acc[2][4];
    mfma_core64<false>(A, 256, Wt, row0, bn0, MROWS, As, Bs, acc);

    const int lane = threadIdx.x & 63;
    const int wv = threadIdx.x >> 6;
    const int wm = (wv & 1) * 32, wn = (wv >> 1) * 64;
    const int l15 = lane & 15, l4 = lane >> 4;

    if (isOff) {
#pragma unroll
        for (int m = 0; m < 2; ++m)
#pragma unroll
            for (int j = 0; j < 4; ++j) {
                int r = row0 + wm + m * 16 + l4 * 4 + j;
                if (r < MROWS) {
                    bf16* orow = offawl + (size_t)r * 384;
#pragma unroll
                    for (int n = 0; n < 4; ++n) {
                        int fcol = bn0 + wn + n * 16 + l15;
                        orow[fcol] = __float2bfloat16(acc[m][n][j] + bias[fcol]);
                    }
                }
            }
    } else {
#pragma unroll
        for (int m = 0; m < 2; ++m)
#pragma unroll
            for (int j = 0; j < 4; ++j) {
                int r = row0 + wm + m * 16 + l4 * 4 + j;
                if (r < MROWS) {
                    int bb = (r >= NQ) ? 1 : 0;
                    int pb = pad_base_idx(r - bb * NQ);
#pragma unroll
                    for (int n = 0; n < 4; ++n) {
                        int fcol = bn0 + wn + n * 16 + l15;
                        int hh = fcol >> 5, cc = fcol & 31;
                        vproj[((size_t)(hh * 2 + bb) * PTOT + pb) * 32 + cc] =
                            (_Float16)(acc[m][n][j] + bias[fcol]);
                    }
                }
            }
    }
}

// ---------------------------------------------------------------------------
// Output GEMM: out = msda(bf16, ld 384) @ W_op^T + b_op + query.
// ---------------------------------------------------------------------------
__global__ __launch_bounds__(256) void gemm_out(
    const bf16* __restrict__ msda, const bf16* __restrict__ Wt_op,
    const float* __restrict__ b_op, const float* __restrict__ query,
    float* __restrict__ out)
{
    __shared__ bf16 As[BM * LDT];
    __shared__ bf16 Bs[128 * 32];

    constexpr int NWG = GX * 2;                 // 1390
    constexpr int QXW = NWG / 8, RXW = NWG % 8; // 173, 6
    int orig = blockIdx.x;
    int xcd = orig & 7, seq = orig >> 3;
    int swz = (xcd < RXW ? xcd * (QXW + 1) : RXW * (QXW + 1) + (xcd - RXW) * QXW) + seq;
    int bn0 = (swz & 1) * 128;
    int row0 = (swz >> 1) * BM;

    f32x4 acc[2][4];
    mfma_core64<true>(msda, 384, Wt_op, row0, bn0, MROWS, As, Bs, acc);

    const int lane = threadIdx.x & 63;
    const int wv = threadIdx.x >> 6;
    const int wm = (wv & 1) * 32, wn = (wv >> 1) * 64;
    const int l15 = lane & 15, l4 = lane >> 4;

#pragma unroll
    for (int m = 0; m < 2; ++m)
#pragma unroll
        for (int j = 0; j < 4; ++j) {
            int r = row0 + wm + m * 16 + l4 * 4 + j;
            if (r < MROWS) {
#pragma unroll
                for (int n = 0; n < 4; ++n) {
                    int fcol = bn0 + wn + n * 16 + l15;
                    out[(size_t)r * 256 + fcol] =
                        acc[m][n][j] + b_op[fcol] + query[(size_t)r * 256 + fcol];
                }
            }
        }
}

// ---------------------------------------------------------------------------
// MSDA sampling v18 (R21 exact best config, waves_per_eu(2,4)): head =
// blockIdx&7 -> XCD affinity; per-XCD L2 holds one head's 3.04 MB slab.
// ---------------------------------------------------------------------------
__device__ inline f32x2 bfpair(unsigned u) {
    f32x2 r;
    r.x = __uint_as_float(u << 16);
    r.y = __uint_as_float(u & 0xffff0000u);
    return r;
}

__global__ __launch_bounds__(256)
__attribute__((amdgpu_waves_per_eu(2, 4)))
void msda_sample18(
    const _Float16* __restrict__ vproj,  // [head][batch][ppix][32] fp16
    const bf16* __restrict__ offawl,     // [MROWS][384] bf16
    const float* __restrict__ refp,
    bf16* __restrict__ msda_out)         // aliases offawl rows (stride 384)
{
    __shared__ uint2 sOff[32][8];        // per-query 64B off head-slice
    __shared__ uint2 sAwl[32][4];        // per-query 32B awl head-slice
    __shared__ float sRef[32][8];

    const int tid = threadIdx.x;
    const int head = blockIdx.x & 7;         // == XCD under round-robin dispatch
    const int qbase = (blockIdx.x >> 3) * 32;

    {   // stage 32 queries' head-slices
        int row = tid >> 3, e = tid & 7;
        int grow = min(qbase + row, MROWS - 1);
        sOff[row][e] = *((const uint2*)(offawl + (size_t)grow * 384 + head * 32) + e);
        sRef[row][e] = refp[(size_t)grow * 8 + e];
        if (tid < 128) {
            int rowa = tid >> 2, ea = tid & 3;
            int growa = min(qbase + rowa, MROWS - 1);
            sAwl[rowa][ea] = *((const uint2*)(offawl + (size_t)growa * 384 + 256 + head * 16) + ea);
        }
    }
    __syncthreads();

    const int w = tid >> 6;       // wave 0..3
    const int lane = tid & 63;
    const int ql = lane >> 3;     // local query within wave
    const int s = lane & 7;
    const int sx = s >> 2;        // x-corner side (consumer role)
    const int c16 = s & 3;        // 16B channel chunk (consumer role)
    const int lq = w * 8 + ql;    // local query within block (0..31)
    int q = qbase + lq;
    const bool alive = q < MROWS;
    if (!alive) q = MROWS - 1;
    const int b = (q >= NQ) ? 1 : 0;

    // ---- cooperative softmax: 2 logits per lane (taps 2s, 2s+1) ----
    float aw0, aw1;
    {
        unsigned lgu = ((const unsigned*)&sAwl[lq][0])[s];
        f32x2 lg = bfpair(lgu);
        float m = fmaxf(lg.x, lg.y);
        m = fmaxf(m, __shfl_xor(m, 1));
        m = fmaxf(m, __shfl_xor(m, 2));
        m = fmaxf(m, __shfl_xor(m, 4));
        float e0 = __expf(lg.x - m), e1 = __expf(lg.y - m);
        float ssum = e0 + e1;
        ssum += __shfl_xor(ssum, 1);
        ssum += __shfl_xor(ssum, 2);
        ssum += __shfl_xor(ssum, 4);
        float inv = 1.f / ssum;
        aw0 = e0 * inv;
        aw1 = e1 * inv;
    }

    // ---- owner geometry for taps 2s, 2s+1 (level s>>1) ----
    int rpix0, rpix1;
    int rw00, rw10, rw01, rw11;   // rwXY: tap Y, x-side X weights (f16x2 bits)
    {
        const int lo = s >> 1;
        const int Wl  = (lo == 0) ? 167 : (lo == 1) ? 84 : (lo == 2) ? 42 : 21;
        const int Hl  = (lo == 0) ? 100 : (lo == 1) ? 50 : (lo == 2) ? 25 : 13;
        const int Wpl = (lo == 0) ? 170 : (lo == 1) ? 87 : (lo == 2) ? 45 : 24;
        const float xb = sRef[lq][lo * 2 + 0] * (float)Wl + 0.5f;
        const float yb = sRef[lq][lo * 2 + 1] * (float)Hl + 0.5f;
        uint2 ou = sOff[lq][s];            // taps 2s, 2s+1 offset pairs
        unsigned ouv[2] = {ou.x, ou.y};
        float awv[2] = {aw0, aw1};
        int pixv[2]; int w0v[2], w1v[2];
#pragma unroll
        for (int k = 0; k < 2; ++k) {
            f32x2 o2 = bfpair(ouv[k]);
            float x = fminf(fmaxf(xb + o2.x, 0.f), (float)(Wl + 1));
            float y = fminf(fmaxf(yb + o2.y, 0.f), (float)(Hl + 1));
            float x0f = floorf(x), y0f = floorf(y);
            float lx = x - x0f, ly = y - y0f;
            float a = awv[k];
            float wy0 = (1.f - ly) * a, wy1 = ly * a;
            float wx0 = 1.f - lx;
            pixv[k] = ((int)y0f * Wpl + (int)x0f) * 32;
            w0v[k] = (int)__builtin_bit_cast(unsigned,
                        f16x2{(_Float16)(wx0 * wy0), (_Float16)(wx0 * wy1)});
            w1v[k] = (int)__builtin_bit_cast(unsigned,
                        f16x2{(_Float16)(lx * wy0), (_Float16)(lx * wy1)});
        }
        rpix0 = pixv[0]; rw00 = w0v[0]; rw10 = w1v[0];
        rpix1 = pixv[1]; rw01 = w0v[1]; rw11 = w1v[1];
    }

    // ---- consumer: gather + accumulate ----
    const int srcbase = lane & 56;
    f16x2 acc0 = {0, 0}, acc1 = {0, 0}, acc2 = {0, 0}, acc3 = {0, 0};

#pragma unroll
    for (int l = 0; l < 4; ++l) {
        const int Wp = PLW[l];
        const _Float16* vl = vproj + ((size_t)(head * 2 + b) * PTOT + PLSTART[l]) * 32
                             + sx * 32 + c16 * 8;

        const _Float16* pr[4][2];
        f16x2 hw0[4], hw1[4];
#pragma unroll
        for (int p = 0; p < 4; ++p) {
            const int t = l * 4 + p;          // compile-time
            const int src = srcbase | (t >> 1);
            int pix, wa, wb;
            if (t & 1) {                       // compile-time parity
                pix = __shfl(rpix1, src);
                wa  = __shfl(rw01, src);
                wb  = __shfl(rw11, src);
            } else {
                pix = __shfl(rpix0, src);
                wa  = __shfl(rw00, src);
                wb  = __shfl(rw10, src);
            }
            f16x2 wv = __builtin_bit_cast(f16x2, (unsigned)(sx ? wb : wa));
            hw0[p] = f16x2{wv[0], wv[0]};
            hw1[p] = f16x2{wv[1], wv[1]};
            pr[p][0] = vl + pix;
            pr[p][1] = pr[p][0] + Wp * 32;
        }

        uint4 c[4][2];
#pragma unroll
        for (int p = 0; p < 4; ++p) {
            c[p][0] = *(const uint4*)pr[p][0];
            c[p][1] = *(const uint4*)pr[p][1];
        }

#pragma unroll
        for (int p = 0; p < 4; ++p) {
            acc0 += __builtin_bit_cast(f16x2, c[p][0].x) * hw0[p];
            acc1 += __builtin_bit_cast(f16x2, c[p][0].y) * hw0[p];
            acc2 += __builtin_bit_cast(f16x2, c[p][0].z) * hw0[p];
            acc3 += __builtin_bit_cast(f16x2, c[p][0].w) * hw0[p];
            acc0 += __builtin_bit_cast(f16x2, c[p][1].x) * hw1[p];
            acc1 += __builtin_bit_cast(f16x2, c[p][1].y) * hw1[p];
            acc2 += __builtin_bit_cast(f16x2, c[p][1].z) * hw1[p];
            acc3 += __builtin_bit_cast(f16x2, c[p][1].w) * hw1[p];
        }
    }

    // combine x0/x1 partial sums across lane pairs (s ^ 4)
    {
        unsigned u0 = __builtin_bit_cast(unsigned, acc0);
        unsigned u1 = __builtin_bit_cast(unsigned, acc1);
        unsigned u2 = __builtin_bit_cast(unsigned, acc2);
        unsigned u3 = __builtin_bit_cast(unsigned, acc3);
        acc0 += __builtin_bit_cast(f16x2, __shfl_xor((int)u0, 4));
        acc1 += __builtin_bit_cast(f16x2, __shfl_xor((int)u1, 4));
        acc2 += __builtin_bit_cast(f16x2, __shfl_xor((int)u2, 4));
        acc3 += __builtin_bit_cast(f16x2, __shfl_xor((int)u3, 4));
    }

    if (alive && sx == 0) {
        bf16 ob[8];
        ob[0] = __float2bfloat16((float)acc0[0]);
        ob[1] = __float2bfloat16((float)acc0[1]);
        ob[2] = __float2bfloat16((float)acc1[0]);
        ob[3] = __float2bfloat16((float)acc1[1]);
        ob[4] = __float2bfloat16((float)acc2[0]);
        ob[5] = __float2bfloat16((float)acc2[1]);
        ob[6] = __float2bfloat16((float)acc3[0]);
        ob[7] = __float2bfloat16((float)acc3[1]);
        *(uint4*)(msda_out + (size_t)q * 384 + head * 32 + c16 * 8) = *(const uint4*)ob;
    }
}

// ---------------------------------------------------------------------------
extern "C" void kernel_launch(void* const* d_in, const int* in_sizes, int n_in,
                              void* d_out, int out_size, void* d_ws, size_t ws_size,
                              hipStream_t stream) {
    const float* query = (const float*)d_in[0];
    const float* value = (const float*)d_in[1];
    const float* refp  = (const float*)d_in[2];
    const float* W_so  = (const float*)d_in[3];
    const float* b_so  = (const float*)d_in[4];
    const float* W_aw  = (const float*)d_in[5];
    const float* b_aw  = (const float*)d_in[6];
    const float* W_vp  = (const float*)d_in[7];
    const float* b_vp  = (const float*)d_in[8];
    const float* W_op  = (const float*)d_in[9];
    const float* b_op  = (const float*)d_in[10];
    float* out = (float*)d_out;

    // Workspace:
    //   offawl : bf16 MROWS*384 (34.1 MB) [off|awl]; msda aliased over rows
    //   vproj  : fp16 16*PTOT*32 (24.3 MB) head-major zero-padded layout
    //   weights: Wt_cat 384*256, Wt_vp/Wt_op 256*256 bf16, bcat 384 f32
    bf16*     d_offawl = (bf16*)d_ws;
    _Float16* d_vproj  = (_Float16*)(d_offawl + (size_t)MROWS * 384);
    bf16*     d_wtcat  = (bf16*)(d_vproj + (size_t)16 * PTOT * 32);
    bf16*     d_wtvp   = d_wtcat + 384 * 256;
    bf16*     d_wtop   = d_wtvp + 256 * 256;
    float*    d_bcat   = (float*)(d_wtop + 256 * 256);

    prep_weights<<<384, 256, 0, stream>>>(W_vp, W_so, W_aw, W_op, b_so, b_aw,
                                          d_wtvp, d_wtcat, d_wtop, d_bcat);
    hipMemsetAsync(d_vproj, 0, (size_t)16 * PTOT * 32 * sizeof(_Float16), stream);

    gemm_producer<<<GX * 5, 256, 0, stream>>>(
        query, value, d_wtcat, d_wtvp, d_bcat, b_vp, d_offawl, d_vproj);

    // 8 heads x 1389 query-chunks; head = blockIdx&7 -> XCD affinity
    msda_sample18<<<8 * ((MROWS + 31) / 32), 256, 0, stream>>>(
        d_vproj, d_offawl, refp, d_offawl);

    gemm_out<<<GX * 2, 256, 0, stream>>>(d_offawl, d_wtop, b_op, query, out);
}